// Round 12
// baseline (331.272 us; speedup 1.0000x reference)
//
#include <hip/hip_runtime.h>
#include <stdint.h>

#define HIDDEN 4096
#define SEQ    2048
#define NHEADS 32
#define HDIM   128
#define KVDIM  1024

typedef __attribute__((ext_vector_type(8))) short short8;
typedef __attribute__((ext_vector_type(4))) unsigned short ushort4v;
typedef __attribute__((ext_vector_type(4))) float f32x4;
typedef __attribute__((ext_vector_type(16))) float f32x16;
typedef __attribute__((ext_vector_type(4))) float float4v;
typedef __attribute__((ext_vector_type(4))) int int4v;

__device__ __forceinline__ unsigned short f2bf(float f) {
    union { float f; unsigned u; } v; v.f = f;
    unsigned r = v.u + 0x7FFFu + ((v.u >> 16) & 1u);
    return (unsigned short)(r >> 16);
}

__device__ __forceinline__ float fexp2(float x) {
#if __has_builtin(__builtin_amdgcn_exp2f)
    return __builtin_amdgcn_exp2f(x);
#else
    return exp2f(x);
#endif
}

__device__ __forceinline__ void store_elem(unsigned short* p, float v) { *p = f2bf(v); }
__device__ __forceinline__ void store_elem(float* p, float v) { *p = v; }

// ------ fused pre-pass: weight transposes + x cast in ONE launch ------
// grid (192, 64): cx<64 wq | <80 wk | <96 wv | <160 wo | 160..191 x-cast
__global__ void prepass_kernel(const float* __restrict__ wq,
                               const float* __restrict__ wk,
                               const float* __restrict__ wv,
                               const float* __restrict__ wo,
                               const float* __restrict__ x,
                               unsigned short* __restrict__ wqkvt,
                               unsigned short* __restrict__ wot,
                               unsigned short* __restrict__ xb) {
    __shared__ float tile[64][65];
    int cx = blockIdx.x;
    int t = threadIdx.x;
    if (cx >= 160) {
        // x cast: 2048 linear blocks x 1024 float4 each
        int bid = (cx - 160) * 64 + blockIdx.y;
        size_t base = (size_t)bid * 1024;
#pragma unroll
        for (int j = 0; j < 4; j++) {
            size_t i = base + t + j * 256;
            float4v v = *(const float4v*)(x + i * 4);
            ushort4v o;
            o.x = f2bf(v.x); o.y = f2bf(v.y); o.z = f2bf(v.z); o.w = f2bf(v.w);
            *(ushort4v*)(xb + i * 4) = o;
        }
        return;
    }
    const float* src; unsigned short* dst; int C; int cxl;
    if (cx < 64)      { src = wq; dst = wqkvt; C = HIDDEN; cxl = cx; }
    else if (cx < 80) { src = wk; dst = wqkvt + (size_t)4096 * HIDDEN; C = KVDIM; cxl = cx - 64; }
    else if (cx < 96) { src = wv; dst = wqkvt + (size_t)5120 * HIDDEN; C = KVDIM; cxl = cx - 80; }
    else              { src = wo; dst = wot;   C = HIDDEN; cxl = cx - 96; }
    const int R = HIDDEN;
    int r0 = blockIdx.y << 6, c0 = cxl << 6;
    int lr = t >> 4, lc = (t & 15) << 2;
#pragma unroll
    for (int i = 0; i < 4; i++) {
        int r = lr + i * 16;
        float4v v = *(const float4v*)(src + (size_t)(r0 + r) * C + c0 + lc);
        tile[r][lc] = v.x; tile[r][lc + 1] = v.y;
        tile[r][lc + 2] = v.z; tile[r][lc + 3] = v.w;
    }
    __syncthreads();
#pragma unroll
    for (int i = 0; i < 4; i++) {
        int c = lr + i * 16;
        ushort4v o;
        o.x = f2bf(tile[lc][c]);     o.y = f2bf(tile[lc + 1][c]);
        o.z = f2bf(tile[lc + 2][c]); o.w = f2bf(tile[lc + 3][c]);
        *(ushort4v*)(dst + (size_t)(c0 + c) * R + r0 + lc) = o;
    }
}

// ---------------- helpers ----------------
__device__ __forceinline__ void gload_lds16(const void* g, void* l) {
    __builtin_amdgcn_global_load_lds(
        (const __attribute__((address_space(1))) void*)g,
        (__attribute__((address_space(3))) void*)l, 16, 0, 0);
}

// =====================================================================
// BK=128 GEMM: LDS holds FOUR back-to-back [128][32] sub-tiles per
// operand (each bit-identical to the R10/R11-verified zero-conflict
// layout: 64B rows, read chunk = fq ^ ((fr>>1)&3), staged via
// pre-swizzled source + linear gload_lds dest). One barrier-pair per
// 128-K (halves barrier/drain count vs BK=64). kk ascending -> bitwise
// identical accumulation. LDS 64KB/block, 2 blocks/CU (128<=160KB).
// =====================================================================

// ---------------- generic GEMM: C[M][N] = (A[M][K] * Bt[N][K]^T + bias) * oscale ----------------
template <typename OT>
__global__ __launch_bounds__(256, 2)
void gemm_bf16_kernel(const unsigned short* __restrict__ A,
                      const unsigned short* __restrict__ Bt,
                      const float* __restrict__ bias,
                      OT* __restrict__ C,
                      int M, int N, int K, float oscale) {
    __shared__ __align__(16) unsigned short As[128 * 128];  // 32KB: sub0..sub3
    __shared__ __align__(16) unsigned short Bs[128 * 128];  // 32KB
    int t = threadIdx.x;
    int w = t >> 6, l = t & 63;
    int wr = w >> 1, wc = w & 1;
    int fr = l & 15, fq = l >> 4;
    int mbase = blockIdx.y << 7, nbase = blockIdx.x << 7;

    int srcch = ((l & 3) ^ ((l >> 3) & 3)) << 3;   // pre-swizzled source chunk (proven)
    const unsigned short* Ap = A + (size_t)(mbase + w * 16 + (l >> 2)) * K + srcch;
    const unsigned short* Bp = Bt + (size_t)(nbase + w * 16 + (l >> 2)) * K + srcch;
    unsigned short* AsW = As + w * 512;
    unsigned short* BsW = Bs + w * 512;
    const size_t rowK64 = (size_t)64 * K;
    int rdo = (fq ^ ((fr >> 1) & 3)) * 8;          // swizzled read chunk (proven)

    f32x4 acc[4][4];
    f32x4 z = {0.f, 0.f, 0.f, 0.f};
#pragma unroll
    for (int m = 0; m < 4; m++)
#pragma unroll
        for (int n = 0; n < 4; n++) acc[m][n] = z;

    for (int kb = 0; kb < K; kb += 128) {
        __syncthreads();
#pragma unroll
        for (int s = 0; s < 4; s++) {
            gload_lds16(Ap + kb + 32 * s,          AsW + s * 4096);
            gload_lds16(Ap + kb + 32 * s + rowK64, AsW + s * 4096 + 2048);
            gload_lds16(Bp + kb + 32 * s,          BsW + s * 4096);
            gload_lds16(Bp + kb + 32 * s + rowK64, BsW + s * 4096 + 2048);
        }
        __syncthreads();
#pragma unroll
        for (int kk = 0; kk < 4; kk++) {
            const unsigned short* Ab = As + kk * 4096;
            const unsigned short* Bb = Bs + kk * 4096;
            short8 a[4], b[4];
#pragma unroll
            for (int m = 0; m < 4; m++)
                a[m] = *(const short8*)(Ab + ((wr * 64 + m * 16 + fr) * 32 + rdo));
#pragma unroll
            for (int n = 0; n < 4; n++)
                b[n] = *(const short8*)(Bb + ((wc * 64 + n * 16 + fr) * 32 + rdo));
#pragma unroll
            for (int m = 0; m < 4; m++)
#pragma unroll
                for (int n = 0; n < 4; n++)
                    acc[m][n] = __builtin_amdgcn_mfma_f32_16x16x32_bf16(a[m], b[n], acc[m][n], 0, 0, 0);
        }
    }

#pragma unroll
    for (int n = 0; n < 4; n++) {
        int col = nbase + wc * 64 + n * 16 + fr;
        float bv = bias[col];
#pragma unroll
        for (int m = 0; m < 4; m++) {
            int row = mbase + wr * 64 + m * 16 + fq * 4;
            OT* cp = C + (size_t)row * N + col;
#pragma unroll
            for (int r = 0; r < 4; r++)
                store_elem(cp + (size_t)r * N, (acc[m][n][r] + bv) * oscale);
        }
    }
}

// ------------- fused Q|K|V GEMM: N=6144 over wqkvt; 3-way epilogue -------------
__global__ __launch_bounds__(256, 2)
void qkv_gemm_kernel(const unsigned short* __restrict__ A,
                     const unsigned short* __restrict__ Bt,
                     const float* __restrict__ bq,
                     const float* __restrict__ bk,
                     const float* __restrict__ bv,
                     unsigned short* __restrict__ Qo,
                     unsigned short* __restrict__ Ko,
                     unsigned short* __restrict__ Vto,
                     float qscale) {
    const int K = HIDDEN;
    __shared__ __align__(16) unsigned short As[128 * 128];
    __shared__ __align__(16) unsigned short Bs[128 * 128];
    int t = threadIdx.x;
    int w = t >> 6, l = t & 63;
    int wr = w >> 1, wc = w & 1;
    int fr = l & 15, fq = l >> 4;
    int mbase = blockIdx.y << 7, nbase = blockIdx.x << 7;

    int srcch = ((l & 3) ^ ((l >> 3) & 3)) << 3;
    const unsigned short* Ap = A + (size_t)(mbase + w * 16 + (l >> 2)) * K + srcch;
    const unsigned short* Bp = Bt + (size_t)(nbase + w * 16 + (l >> 2)) * K + srcch;
    unsigned short* AsW = As + w * 512;
    unsigned short* BsW = Bs + w * 512;
    const size_t rowK64 = (size_t)64 * K;
    int rdo = (fq ^ ((fr >> 1) & 3)) * 8;

    f32x4 acc[4][4];
    f32x4 z = {0.f, 0.f, 0.f, 0.f};
#pragma unroll
    for (int m = 0; m < 4; m++)
#pragma unroll
        for (int n = 0; n < 4; n++) acc[m][n] = z;

    for (int kb = 0; kb < K; kb += 128) {
        __syncthreads();
#pragma unroll
        for (int s = 0; s < 4; s++) {
            gload_lds16(Ap + kb + 32 * s,          AsW + s * 4096);
            gload_lds16(Ap + kb + 32 * s + rowK64, AsW + s * 4096 + 2048);
            gload_lds16(Bp + kb + 32 * s,          BsW + s * 4096);
            gload_lds16(Bp + kb + 32 * s + rowK64, BsW + s * 4096 + 2048);
        }
        __syncthreads();
#pragma unroll
        for (int kk = 0; kk < 4; kk++) {
            const unsigned short* Ab = As + kk * 4096;
            const unsigned short* Bb = Bs + kk * 4096;
            short8 a[4], b[4];
#pragma unroll
            for (int m = 0; m < 4; m++)
                a[m] = *(const short8*)(Ab + ((wr * 64 + m * 16 + fr) * 32 + rdo));
#pragma unroll
            for (int n = 0; n < 4; n++)
                b[n] = *(const short8*)(Bb + ((wc * 64 + n * 16 + fr) * 32 + rdo));
#pragma unroll
            for (int m = 0; m < 4; m++)
#pragma unroll
                for (int n = 0; n < 4; n++)
                    acc[m][n] = __builtin_amdgcn_mfma_f32_16x16x32_bf16(a[m], b[n], acc[m][n], 0, 0, 0);
        }
    }

    if (nbase < 4096) {
#pragma unroll
        for (int n = 0; n < 4; n++) {
            int col = nbase + wc * 64 + n * 16 + fr;
            float bb = bq[col];
#pragma unroll
            for (int m = 0; m < 4; m++) {
                int row = mbase + wr * 64 + m * 16 + fq * 4;
                unsigned short* cp = Qo + (size_t)row * HIDDEN + col;
#pragma unroll
                for (int r = 0; r < 4; r++)
                    cp[(size_t)r * HIDDEN] = f2bf((acc[m][n][r] + bb) * qscale);
            }
        }
    } else if (nbase < 5120) {
#pragma unroll
        for (int n = 0; n < 4; n++) {
            int col = nbase - 4096 + wc * 64 + n * 16 + fr;
            float bb = bk[col];
#pragma unroll
            for (int m = 0; m < 4; m++) {
                int row = mbase + wr * 64 + m * 16 + fq * 4;
                unsigned short* cp = Ko + (size_t)row * KVDIM + col;
#pragma unroll
                for (int r = 0; r < 4; r++)
                    cp[(size_t)r * KVDIM] = f2bf(acc[m][n][r] + bb);
            }
        }
    } else {
#pragma unroll
        for (int n = 0; n < 4; n++) {
            int colv = nbase - 5120 + wc * 64 + n * 16 + fr;
            float bb = bv[colv];
#pragma unroll
            for (int m = 0; m < 4; m++) {
                int row = mbase + wr * 64 + m * 16 + fq * 4;
                ushort4v o;
                o.x = f2bf(acc[m][n][0] + bb);
                o.y = f2bf(acc[m][n][1] + bb);
                o.z = f2bf(acc[m][n][2] + bb);
                o.w = f2bf(acc[m][n][3] + bb);
                *(ushort4v*)(Vto + (size_t)colv * SEQ + row) = o;
            }
        }
    }
}

// ---------------- flash attention v4 (R10/R11-proven, unchanged) ----------------
#define SWZ(off, row) ((off) ^ (((row) & 7) << 4))
__global__ __launch_bounds__(512, 2)
void attn_kernel(const unsigned short* __restrict__ Q,
                 const unsigned short* __restrict__ Kc,
                 const unsigned short* __restrict__ Vt,
                 unsigned short* __restrict__ Mg) {
    __shared__ __align__(16) char Kb[2][64 * 256];
    __shared__ __align__(16) char Vb[2][128 * 128];
    int qb = blockIdx.x, head = blockIdx.y, g = head >> 2;
    int t = threadIdx.x, w = t >> 6, l = t & 63;
    int lq = l & 31, lh = l >> 5;

    short8 qf[8];
    {
        const unsigned short* qp =
            Q + (size_t)(qb * 256 + w * 32 + lq) * HIDDEN + head * HDIM + lh * 8;
#pragma unroll
        for (int kk = 0; kk < 8; kk++) qf[kk] = *(const short8*)(qp + kk * 16);
    }

    f32x16 accO[4];
#pragma unroll
    for (int n = 0; n < 4; n++)
#pragma unroll
        for (int r = 0; r < 16; r++) accO[n][r] = 0.f;
    float Lrun = 0.f;

    int krow = t >> 3; int kcb = (t & 7) * 32;
    int vrow = t >> 2; int vcb = (t & 3) * 32;
    const unsigned short* ksrc = Kc + (size_t)krow * KVDIM + g * HDIM + (t & 7) * 16;
    const unsigned short* vsrc = Vt + (size_t)(g * HDIM + vrow) * SEQ + (t & 3) * 16;
    int kwb = krow * 256 + kcb;
    int vwb = vrow * 128 + vcb;

    const int NT = SEQ / 64;
    short8 kreg[2], vreg[2];
#pragma unroll
    for (int j = 0; j < 2; j++) kreg[j] = *(const short8*)(ksrc + j * 8);
#pragma unroll
    for (int j = 0; j < 2; j++) vreg[j] = *(const short8*)(vsrc + j * 8);
#pragma unroll
    for (int j = 0; j < 2; j++) *(short8*)(Kb[0] + SWZ(kwb + j * 16, krow)) = kreg[j];
#pragma unroll
    for (int j = 0; j < 2; j++) *(short8*)(Vb[0] + SWZ(vwb + j * 16, vrow)) = vreg[j];
#pragma unroll
    for (int j = 0; j < 2; j++) kreg[j] = *(const short8*)(ksrc + (size_t)64 * KVDIM + j * 8);
#pragma unroll
    for (int j = 0; j < 2; j++) vreg[j] = *(const short8*)(vsrc + 64 + j * 8);

    for (int tl = 0; tl < NT; tl++) {
        int b = tl & 1;
        __syncthreads();
        if (tl + 1 < NT) {
#pragma unroll
            for (int j = 0; j < 2; j++) *(short8*)(Kb[b ^ 1] + SWZ(kwb + j * 16, krow)) = kreg[j];
#pragma unroll
            for (int j = 0; j < 2; j++) *(short8*)(Vb[b ^ 1] + SWZ(vwb + j * 16, vrow)) = vreg[j];
            if (tl + 2 < NT) {
                const unsigned short* ks = ksrc + (size_t)(tl + 2) * 64 * KVDIM;
                const unsigned short* vs = vsrc + (tl + 2) * 64;
#pragma unroll
                for (int j = 0; j < 2; j++) kreg[j] = *(const short8*)(ks + j * 8);
#pragma unroll
                for (int j = 0; j < 2; j++) vreg[j] = *(const short8*)(vs + j * 8);
            }
        }
        const char* kb = Kb[b];
        const char* vb = Vb[b];

        f32x16 s0, s1;
#pragma unroll
        for (int r = 0; r < 16; r++) { s0[r] = 0.f; s1[r] = 0.f; }
#pragma unroll
        for (int kk = 0; kk < 8; kk++) {
            int cb2 = kk * 32 + lh * 16;
            short8 kf0 = *(const short8*)(kb + SWZ(lq * 256 + cb2, lq));
            short8 kf1 = *(const short8*)(kb + SWZ((lq + 32) * 256 + cb2, lq));
            s0 = __builtin_amdgcn_mfma_f32_32x32x16_bf16(kf0, qf[kk], s0, 0, 0, 0);
            s1 = __builtin_amdgcn_mfma_f32_32x32x16_bf16(kf1, qf[kk], s1, 0, 0, 0);
        }

        float sum = 0.f;
#pragma unroll
        for (int r = 0; r < 16; r++) { s0[r] = fexp2(s0[r]); sum += s0[r]; }
#pragma unroll
        for (int r = 0; r < 16; r++) { s1[r] = fexp2(s1[r]); sum += s1[r]; }
        sum += __shfl_xor(sum, 32);
        Lrun += sum;

        int W0[8], W1[8];
#pragma unroll
        for (int i = 0; i < 8; i++)
            W0[i] = (int)((unsigned)f2bf(s0[2 * i]) | ((unsigned)f2bf(s0[2 * i + 1]) << 16));
#pragma unroll
        for (int i = 0; i < 8; i++)
            W1[i] = (int)((unsigned)f2bf(s1[2 * i]) | ((unsigned)f2bf(s1[2 * i + 1]) << 16));

        short8 pa[4];
#pragma unroll
        for (int kkp = 0; kkp < 4; kkp++) {
            int k4 = (kkp & 1) * 4;
            int o0 = (kkp < 2) ? W0[k4 + 0] : W1[k4 + 0];
            int o1 = (kkp < 2) ? W0[k4 + 1] : W1[k4 + 1];
            int o2 = (kkp < 2) ? W0[k4 + 2] : W1[k4 + 2];
            int o3 = (kkp < 2) ? W0[k4 + 3] : W1[k4 + 3];
            int Za = lh ? o0 : o2;
            int Zb = lh ? o1 : o3;
            int Xa = __shfl_xor(Za, 32);
            int Xb = __shfl_xor(Zb, 32);
            int4v pw;
            pw.x = lh ? Xa : o0;
            pw.y = lh ? Xb : o1;
            pw.z = lh ? o2 : Xa;
            pw.w = lh ? o3 : Xb;
            pa[kkp] = *(short8*)&pw;
        }

#pragma unroll
        for (int n = 0; n < 4; n++) {
            int row = n * 32 + lq;
#pragma unroll
            for (int kkp = 0; kkp < 4; kkp++) {
                short8 vf = *(const short8*)(vb + SWZ(row * 128 + kkp * 32 + lh * 16, lq));
                accO[n] = __builtin_amdgcn_mfma_f32_32x32x16_bf16(pa[kkp], vf, accO[n], 0, 0, 0);
            }
        }
    }

    float rl[16];
#pragma unroll
    for (int r = 0; r < 16; r++)
        rl[r] = 1.0f / __shfl(Lrun, (r & 3) + 8 * (r >> 2) + 4 * lh);
#pragma unroll
    for (int n = 0; n < 4; n++) {
        int d = n * 32 + lq;
        int mrow = head * 64 + (d >> 1);
#pragma unroll
        for (int g2 = 0; g2 < 4; g2++) {
            int mcol = (d & 1) * SEQ + qb * 256 + w * 32 + 8 * g2 + 4 * lh;
            ushort4v o;
            o.x = f2bf(accO[n][g2 * 4 + 0] * rl[g2 * 4 + 0]);
            o.y = f2bf(accO[n][g2 * 4 + 1] * rl[g2 * 4 + 1]);
            o.z = f2bf(accO[n][g2 * 4 + 2] * rl[g2 * 4 + 2]);
            o.w = f2bf(accO[n][g2 * 4 + 3] * rl[g2 * 4 + 3]);
            *(ushort4v*)(Mg + (size_t)mrow * HIDDEN + mcol) = o;
        }
    }
}

// ---------------------------------------------------------------------
extern "C" void kernel_launch(void* const* d_in, const int* in_sizes, int n_in,
                              void* d_out, int out_size, void* d_ws, size_t ws_size,
                              hipStream_t stream) {
    const float* x  = (const float*)d_in[0];
    const float* wq = (const float*)d_in[1];
    const float* bq = (const float*)d_in[2];
    const float* wk = (const float*)d_in[3];
    const float* bk = (const float*)d_in[4];
    const float* wv = (const float*)d_in[5];
    const float* bv = (const float*)d_in[6];
    const float* wo = (const float*)d_in[7];
    const float* bo = (const float*)d_in[8];

    // Flat workspace, 142.6 MB total (proven OK R4-R11)
    char* base = (char*)d_ws;
    unsigned short* xb     = (unsigned short*)(base + 0);          // 16.8M
    unsigned short* wqkvt  = (unsigned short*)(base + 16777216);   // 50.3M
    unsigned short* wot    = (unsigned short*)(base + 67108864);   // 33.6M
    unsigned short* qbuf   = (unsigned short*)(base + 100663296);  // 16.8M
    unsigned short* kbuf   = (unsigned short*)(base + 117440512);  // 4.2M
    unsigned short* vtbuf  = (unsigned short*)(base + 121634816);  // 4.2M
    unsigned short* merged = (unsigned short*)(base + 125829120);  // 16.8M

    const float QSCALE = 0.08838834764831845f * 1.4426950408889634f;  // 1/sqrt(128) * log2(e)

    // 1) fused pre-pass: weight transposes + x cast (one launch)
    prepass_kernel<<<dim3(192, 64), 256, 0, stream>>>(wq, wk, wv, wo, x, wqkvt, wot, xb);
    // 2) fused Q|K|V projection (BK=128; grid 48x16=768)
    qkv_gemm_kernel<<<dim3(6144 / 128, SEQ / 128), 256, 0, stream>>>(
        xb, wqkvt, bq, bk, bv, qbuf, kbuf, vtbuf, QSCALE);
    // 3) flash attention into merged (QBLK=256, 512 thr, grid 8x32)
    attn_kernel<<<dim3(SEQ / 256, NHEADS), 512, 0, stream>>>(qbuf, kbuf, vtbuf, merged);
    // 4) output projection -> fp32 d_out (BK=128; grid 32x16=512)
    gemm_bf16_kernel<<<dim3(HIDDEN / 128, SEQ / 128), 256, 0, stream>>>(
        merged, wot, bo, (float*)d_out, SEQ, HIDDEN, HIDDEN, 1.0f);
}

// Round 13
// 312.571 us; speedup vs baseline: 1.0598x; 1.0598x over previous
//
#include <hip/hip_runtime.h>
#include <stdint.h>

#define HIDDEN 4096
#define SEQ    2048
#define NHEADS 32
#define HDIM   128
#define KVDIM  1024

typedef __attribute__((ext_vector_type(8))) short short8;
typedef __attribute__((ext_vector_type(4))) unsigned short ushort4v;
typedef __attribute__((ext_vector_type(4))) float f32x4;
typedef __attribute__((ext_vector_type(16))) float f32x16;
typedef __attribute__((ext_vector_type(4))) float float4v;
typedef __attribute__((ext_vector_type(4))) int int4v;

__device__ __forceinline__ unsigned short f2bf(float f) {
    union { float f; unsigned u; } v; v.f = f;
    unsigned r = v.u + 0x7FFFu + ((v.u >> 16) & 1u);
    return (unsigned short)(r >> 16);
}

__device__ __forceinline__ float fexp2(float x) {
#if __has_builtin(__builtin_amdgcn_exp2f)
    return __builtin_amdgcn_exp2f(x);
#else
    return exp2f(x);
#endif
}

__device__ __forceinline__ void store_elem(unsigned short* p, float v) { *p = f2bf(v); }
__device__ __forceinline__ void store_elem(float* p, float v) { *p = v; }

// ------ fused pre-pass: weight transposes + x cast in ONE launch (R12-proven) ------
// grid (192, 64): cx<64 wq | <80 wk | <96 wv | <160 wo | 160..191 x-cast
__global__ void prepass_kernel(const float* __restrict__ wq,
                               const float* __restrict__ wk,
                               const float* __restrict__ wv,
                               const float* __restrict__ wo,
                               const float* __restrict__ x,
                               unsigned short* __restrict__ wqkvt,
                               unsigned short* __restrict__ wot,
                               unsigned short* __restrict__ xb) {
    __shared__ float tile[64][65];
    int cx = blockIdx.x;
    int t = threadIdx.x;
    if (cx >= 160) {
        int bid = (cx - 160) * 64 + blockIdx.y;
        size_t base = (size_t)bid * 1024;
#pragma unroll
        for (int j = 0; j < 4; j++) {
            size_t i = base + t + j * 256;
            float4v v = *(const float4v*)(x + i * 4);
            ushort4v o;
            o.x = f2bf(v.x); o.y = f2bf(v.y); o.z = f2bf(v.z); o.w = f2bf(v.w);
            *(ushort4v*)(xb + i * 4) = o;
        }
        return;
    }
    const float* src; unsigned short* dst; int C; int cxl;
    if (cx < 64)      { src = wq; dst = wqkvt; C = HIDDEN; cxl = cx; }
    else if (cx < 80) { src = wk; dst = wqkvt + (size_t)4096 * HIDDEN; C = KVDIM; cxl = cx - 64; }
    else if (cx < 96) { src = wv; dst = wqkvt + (size_t)5120 * HIDDEN; C = KVDIM; cxl = cx - 80; }
    else              { src = wo; dst = wot;   C = HIDDEN; cxl = cx - 96; }
    const int R = HIDDEN;
    int r0 = blockIdx.y << 6, c0 = cxl << 6;
    int lr = t >> 4, lc = (t & 15) << 2;
#pragma unroll
    for (int i = 0; i < 4; i++) {
        int r = lr + i * 16;
        float4v v = *(const float4v*)(src + (size_t)(r0 + r) * C + c0 + lc);
        tile[r][lc] = v.x; tile[r][lc + 1] = v.y;
        tile[r][lc + 2] = v.z; tile[r][lc + 3] = v.w;
    }
    __syncthreads();
#pragma unroll
    for (int i = 0; i < 4; i++) {
        int c = lr + i * 16;
        ushort4v o;
        o.x = f2bf(tile[lc][c]);     o.y = f2bf(tile[lc + 1][c]);
        o.z = f2bf(tile[lc + 2][c]); o.w = f2bf(tile[lc + 3][c]);
        *(ushort4v*)(dst + (size_t)(c0 + c) * R + r0 + lc) = o;
    }
}

// ---------------- helpers ----------------
__device__ __forceinline__ void gload_lds16(const void* g, void* l) {
    __builtin_amdgcn_global_load_lds(
        (const __attribute__((address_space(1))) void*)g,
        (__attribute__((address_space(3))) void*)l, 16, 0, 0);
}

// =====================================================================
// R11-proven BK=64 GEMM (best measured config): LDS = TWO back-to-back
// [128][32] zero-conflict sub-tiles per operand (64B rows, read chunk =
// fq ^ ((fr>>1)&3), pre-swizzled source + linear gload_lds dest).
// 32KB LDS/block keeps full occupancy (m132 lesson: 64KB halves it).
// =====================================================================

// ---------------- generic GEMM: C[M][N] = (A[M][K] * Bt[N][K]^T + bias) * oscale ----------------
template <typename OT>
__global__ __launch_bounds__(256, 2)
void gemm_bf16_kernel(const unsigned short* __restrict__ A,
                      const unsigned short* __restrict__ Bt,
                      const float* __restrict__ bias,
                      OT* __restrict__ C,
                      int M, int N, int K, float oscale) {
    __shared__ __align__(16) unsigned short As[128 * 64];  // 16KB: sub0 | sub1
    __shared__ __align__(16) unsigned short Bs[128 * 64];  // 16KB
    int t = threadIdx.x;
    int w = t >> 6, l = t & 63;
    int wr = w >> 1, wc = w & 1;
    int fr = l & 15, fq = l >> 4;
    int mbase = blockIdx.y << 7, nbase = blockIdx.x << 7;

    int srcch = ((l & 3) ^ ((l >> 3) & 3)) << 3;
    const unsigned short* Ap = A + (size_t)(mbase + w * 16 + (l >> 2)) * K + srcch;
    const unsigned short* Bp = Bt + (size_t)(nbase + w * 16 + (l >> 2)) * K + srcch;
    unsigned short* AsW = As + w * 512;
    unsigned short* BsW = Bs + w * 512;
    const size_t rowK64 = (size_t)64 * K;
    int rdo = (fq ^ ((fr >> 1) & 3)) * 8;

    f32x4 acc[4][4];
    f32x4 z = {0.f, 0.f, 0.f, 0.f};
#pragma unroll
    for (int m = 0; m < 4; m++)
#pragma unroll
        for (int n = 0; n < 4; n++) acc[m][n] = z;

    for (int kb = 0; kb < K; kb += 64) {
        __syncthreads();
        gload_lds16(Ap + kb,               AsW);
        gload_lds16(Ap + kb + rowK64,      AsW + 2048);
        gload_lds16(Ap + kb + 32,          AsW + 4096);
        gload_lds16(Ap + kb + 32 + rowK64, AsW + 6144);
        gload_lds16(Bp + kb,               BsW);
        gload_lds16(Bp + kb + rowK64,      BsW + 2048);
        gload_lds16(Bp + kb + 32,          BsW + 4096);
        gload_lds16(Bp + kb + 32 + rowK64, BsW + 6144);
        __syncthreads();
#pragma unroll
        for (int kk = 0; kk < 2; kk++) {
            const unsigned short* Ab = As + kk * 4096;
            const unsigned short* Bb = Bs + kk * 4096;
            short8 a[4], b[4];
#pragma unroll
            for (int m = 0; m < 4; m++)
                a[m] = *(const short8*)(Ab + ((wr * 64 + m * 16 + fr) * 32 + rdo));
#pragma unroll
            for (int n = 0; n < 4; n++)
                b[n] = *(const short8*)(Bb + ((wc * 64 + n * 16 + fr) * 32 + rdo));
#pragma unroll
            for (int m = 0; m < 4; m++)
#pragma unroll
                for (int n = 0; n < 4; n++)
                    acc[m][n] = __builtin_amdgcn_mfma_f32_16x16x32_bf16(a[m], b[n], acc[m][n], 0, 0, 0);
        }
    }

#pragma unroll
    for (int n = 0; n < 4; n++) {
        int col = nbase + wc * 64 + n * 16 + fr;
        float bv = bias[col];
#pragma unroll
        for (int m = 0; m < 4; m++) {
            int row = mbase + wr * 64 + m * 16 + fq * 4;
            OT* cp = C + (size_t)row * N + col;
#pragma unroll
            for (int r = 0; r < 4; r++)
                store_elem(cp + (size_t)r * N, (acc[m][n][r] + bv) * oscale);
        }
    }
}

// ------------- fused Q|K|V GEMM: N=6144 over wqkvt; 3-way epilogue -------------
__global__ __launch_bounds__(256, 2)
void qkv_gemm_kernel(const unsigned short* __restrict__ A,
                     const unsigned short* __restrict__ Bt,
                     const float* __restrict__ bq,
                     const float* __restrict__ bk,
                     const float* __restrict__ bv,
                     unsigned short* __restrict__ Qo,
                     unsigned short* __restrict__ Ko,
                     unsigned short* __restrict__ Vto,
                     float qscale) {
    const int K = HIDDEN;
    __shared__ __align__(16) unsigned short As[128 * 64];
    __shared__ __align__(16) unsigned short Bs[128 * 64];
    int t = threadIdx.x;
    int w = t >> 6, l = t & 63;
    int wr = w >> 1, wc = w & 1;
    int fr = l & 15, fq = l >> 4;
    int mbase = blockIdx.y << 7, nbase = blockIdx.x << 7;

    int srcch = ((l & 3) ^ ((l >> 3) & 3)) << 3;
    const unsigned short* Ap = A + (size_t)(mbase + w * 16 + (l >> 2)) * K + srcch;
    const unsigned short* Bp = Bt + (size_t)(nbase + w * 16 + (l >> 2)) * K + srcch;
    unsigned short* AsW = As + w * 512;
    unsigned short* BsW = Bs + w * 512;
    const size_t rowK64 = (size_t)64 * K;
    int rdo = (fq ^ ((fr >> 1) & 3)) * 8;

    f32x4 acc[4][4];
    f32x4 z = {0.f, 0.f, 0.f, 0.f};
#pragma unroll
    for (int m = 0; m < 4; m++)
#pragma unroll
        for (int n = 0; n < 4; n++) acc[m][n] = z;

    for (int kb = 0; kb < K; kb += 64) {
        __syncthreads();
        gload_lds16(Ap + kb,               AsW);
        gload_lds16(Ap + kb + rowK64,      AsW + 2048);
        gload_lds16(Ap + kb + 32,          AsW + 4096);
        gload_lds16(Ap + kb + 32 + rowK64, AsW + 6144);
        gload_lds16(Bp + kb,               BsW);
        gload_lds16(Bp + kb + rowK64,      BsW + 2048);
        gload_lds16(Bp + kb + 32,          BsW + 4096);
        gload_lds16(Bp + kb + 32 + rowK64, BsW + 6144);
        __syncthreads();
#pragma unroll
        for (int kk = 0; kk < 2; kk++) {
            const unsigned short* Ab = As + kk * 4096;
            const unsigned short* Bb = Bs + kk * 4096;
            short8 a[4], b[4];
#pragma unroll
            for (int m = 0; m < 4; m++)
                a[m] = *(const short8*)(Ab + ((wr * 64 + m * 16 + fr) * 32 + rdo));
#pragma unroll
            for (int n = 0; n < 4; n++)
                b[n] = *(const short8*)(Bb + ((wc * 64 + n * 16 + fr) * 32 + rdo));
#pragma unroll
            for (int m = 0; m < 4; m++)
#pragma unroll
                for (int n = 0; n < 4; n++)
                    acc[m][n] = __builtin_amdgcn_mfma_f32_16x16x32_bf16(a[m], b[n], acc[m][n], 0, 0, 0);
        }
    }

    if (nbase < 4096) {
#pragma unroll
        for (int n = 0; n < 4; n++) {
            int col = nbase + wc * 64 + n * 16 + fr;
            float bb = bq[col];
#pragma unroll
            for (int m = 0; m < 4; m++) {
                int row = mbase + wr * 64 + m * 16 + fq * 4;
                unsigned short* cp = Qo + (size_t)row * HIDDEN + col;
#pragma unroll
                for (int r = 0; r < 4; r++)
                    cp[(size_t)r * HIDDEN] = f2bf((acc[m][n][r] + bb) * qscale);
            }
        }
    } else if (nbase < 5120) {
#pragma unroll
        for (int n = 0; n < 4; n++) {
            int col = nbase - 4096 + wc * 64 + n * 16 + fr;
            float bb = bk[col];
#pragma unroll
            for (int m = 0; m < 4; m++) {
                int row = mbase + wr * 64 + m * 16 + fq * 4;
                unsigned short* cp = Ko + (size_t)row * KVDIM + col;
#pragma unroll
                for (int r = 0; r < 4; r++)
                    cp[(size_t)r * KVDIM] = f2bf(acc[m][n][r] + bb);
            }
        }
    } else {
#pragma unroll
        for (int n = 0; n < 4; n++) {
            int colv = nbase - 5120 + wc * 64 + n * 16 + fr;
            float bb = bv[colv];
#pragma unroll
            for (int m = 0; m < 4; m++) {
                int row = mbase + wr * 64 + m * 16 + fq * 4;
                ushort4v o;
                o.x = f2bf(acc[m][n][0] + bb);
                o.y = f2bf(acc[m][n][1] + bb);
                o.z = f2bf(acc[m][n][2] + bb);
                o.w = f2bf(acc[m][n][3] + bb);
                *(ushort4v*)(Vto + (size_t)colv * SEQ + row) = o;
            }
        }
    }
}

// ---------------- flash attention v4 (R10/R11-proven, unchanged) ----------------
#define SWZ(off, row) ((off) ^ (((row) & 7) << 4))
__global__ __launch_bounds__(512, 2)
void attn_kernel(const unsigned short* __restrict__ Q,
                 const unsigned short* __restrict__ Kc,
                 const unsigned short* __restrict__ Vt,
                 unsigned short* __restrict__ Mg) {
    __shared__ __align__(16) char Kb[2][64 * 256];
    __shared__ __align__(16) char Vb[2][128 * 128];
    int qb = blockIdx.x, head = blockIdx.y, g = head >> 2;
    int t = threadIdx.x, w = t >> 6, l = t & 63;
    int lq = l & 31, lh = l >> 5;

    short8 qf[8];
    {
        const unsigned short* qp =
            Q + (size_t)(qb * 256 + w * 32 + lq) * HIDDEN + head * HDIM + lh * 8;
#pragma unroll
        for (int kk = 0; kk < 8; kk++) qf[kk] = *(const short8*)(qp + kk * 16);
    }

    f32x16 accO[4];
#pragma unroll
    for (int n = 0; n < 4; n++)
#pragma unroll
        for (int r = 0; r < 16; r++) accO[n][r] = 0.f;
    float Lrun = 0.f;

    int krow = t >> 3; int kcb = (t & 7) * 32;
    int vrow = t >> 2; int vcb = (t & 3) * 32;
    const unsigned short* ksrc = Kc + (size_t)krow * KVDIM + g * HDIM + (t & 7) * 16;
    const unsigned short* vsrc = Vt + (size_t)(g * HDIM + vrow) * SEQ + (t & 3) * 16;
    int kwb = krow * 256 + kcb;
    int vwb = vrow * 128 + vcb;

    const int NT = SEQ / 64;
    short8 kreg[2], vreg[2];
#pragma unroll
    for (int j = 0; j < 2; j++) kreg[j] = *(const short8*)(ksrc + j * 8);
#pragma unroll
    for (int j = 0; j < 2; j++) vreg[j] = *(const short8*)(vsrc + j * 8);
#pragma unroll
    for (int j = 0; j < 2; j++) *(short8*)(Kb[0] + SWZ(kwb + j * 16, krow)) = kreg[j];
#pragma unroll
    for (int j = 0; j < 2; j++) *(short8*)(Vb[0] + SWZ(vwb + j * 16, vrow)) = vreg[j];
#pragma unroll
    for (int j = 0; j < 2; j++) kreg[j] = *(const short8*)(ksrc + (size_t)64 * KVDIM + j * 8);
#pragma unroll
    for (int j = 0; j < 2; j++) vreg[j] = *(const short8*)(vsrc + 64 + j * 8);

    for (int tl = 0; tl < NT; tl++) {
        int b = tl & 1;
        __syncthreads();
        if (tl + 1 < NT) {
#pragma unroll
            for (int j = 0; j < 2; j++) *(short8*)(Kb[b ^ 1] + SWZ(kwb + j * 16, krow)) = kreg[j];
#pragma unroll
            for (int j = 0; j < 2; j++) *(short8*)(Vb[b ^ 1] + SWZ(vwb + j * 16, vrow)) = vreg[j];
            if (tl + 2 < NT) {
                const unsigned short* ks = ksrc + (size_t)(tl + 2) * 64 * KVDIM;
                const unsigned short* vs = vsrc + (tl + 2) * 64;
#pragma unroll
                for (int j = 0; j < 2; j++) kreg[j] = *(const short8*)(ks + j * 8);
#pragma unroll
                for (int j = 0; j < 2; j++) vreg[j] = *(const short8*)(vs + j * 8);
            }
        }
        const char* kb = Kb[b];
        const char* vb = Vb[b];

        f32x16 s0, s1;
#pragma unroll
        for (int r = 0; r < 16; r++) { s0[r] = 0.f; s1[r] = 0.f; }
#pragma unroll
        for (int kk = 0; kk < 8; kk++) {
            int cb2 = kk * 32 + lh * 16;
            short8 kf0 = *(const short8*)(kb + SWZ(lq * 256 + cb2, lq));
            short8 kf1 = *(const short8*)(kb + SWZ((lq + 32) * 256 + cb2, lq));
            s0 = __builtin_amdgcn_mfma_f32_32x32x16_bf16(kf0, qf[kk], s0, 0, 0, 0);
            s1 = __builtin_amdgcn_mfma_f32_32x32x16_bf16(kf1, qf[kk], s1, 0, 0, 0);
        }

        float sum = 0.f;
#pragma unroll
        for (int r = 0; r < 16; r++) { s0[r] = fexp2(s0[r]); sum += s0[r]; }
#pragma unroll
        for (int r = 0; r < 16; r++) { s1[r] = fexp2(s1[r]); sum += s1[r]; }
        sum += __shfl_xor(sum, 32);
        Lrun += sum;

        int W0[8], W1[8];
#pragma unroll
        for (int i = 0; i < 8; i++)
            W0[i] = (int)((unsigned)f2bf(s0[2 * i]) | ((unsigned)f2bf(s0[2 * i + 1]) << 16));
#pragma unroll
        for (int i = 0; i < 8; i++)
            W1[i] = (int)((unsigned)f2bf(s1[2 * i]) | ((unsigned)f2bf(s1[2 * i + 1]) << 16));

        short8 pa[4];
#pragma unroll
        for (int kkp = 0; kkp < 4; kkp++) {
            int k4 = (kkp & 1) * 4;
            int o0 = (kkp < 2) ? W0[k4 + 0] : W1[k4 + 0];
            int o1 = (kkp < 2) ? W0[k4 + 1] : W1[k4 + 1];
            int o2 = (kkp < 2) ? W0[k4 + 2] : W1[k4 + 2];
            int o3 = (kkp < 2) ? W0[k4 + 3] : W1[k4 + 3];
            int Za = lh ? o0 : o2;
            int Zb = lh ? o1 : o3;
            int Xa = __shfl_xor(Za, 32);
            int Xb = __shfl_xor(Zb, 32);
            int4v pw;
            pw.x = lh ? Xa : o0;
            pw.y = lh ? Xb : o1;
            pw.z = lh ? o2 : Xa;
            pw.w = lh ? o3 : Xb;
            pa[kkp] = *(short8*)&pw;
        }

#pragma unroll
        for (int n = 0; n < 4; n++) {
            int row = n * 32 + lq;
#pragma unroll
            for (int kkp = 0; kkp < 4; kkp++) {
                short8 vf = *(const short8*)(vb + SWZ(row * 128 + kkp * 32 + lh * 16, lq));
                accO[n] = __builtin_amdgcn_mfma_f32_32x32x16_bf16(pa[kkp], vf, accO[n], 0, 0, 0);
            }
        }
    }

    float rl[16];
#pragma unroll
    for (int r = 0; r < 16; r++)
        rl[r] = 1.0f / __shfl(Lrun, (r & 3) + 8 * (r >> 2) + 4 * lh);
#pragma unroll
    for (int n = 0; n < 4; n++) {
        int d = n * 32 + lq;
        int mrow = head * 64 + (d >> 1);
#pragma unroll
        for (int g2 = 0; g2 < 4; g2++) {
            int mcol = (d & 1) * SEQ + qb * 256 + w * 32 + 8 * g2 + 4 * lh;
            ushort4v o;
            o.x = f2bf(accO[n][g2 * 4 + 0] * rl[g2 * 4 + 0]);
            o.y = f2bf(accO[n][g2 * 4 + 1] * rl[g2 * 4 + 1]);
            o.z = f2bf(accO[n][g2 * 4 + 2] * rl[g2 * 4 + 2]);
            o.w = f2bf(accO[n][g2 * 4 + 3] * rl[g2 * 4 + 3]);
            *(ushort4v*)(Mg + (size_t)mrow * HIDDEN + mcol) = o;
        }
    }
}

// ---------------------------------------------------------------------
extern "C" void kernel_launch(void* const* d_in, const int* in_sizes, int n_in,
                              void* d_out, int out_size, void* d_ws, size_t ws_size,
                              hipStream_t stream) {
    const float* x  = (const float*)d_in[0];
    const float* wq = (const float*)d_in[1];
    const float* bq = (const float*)d_in[2];
    const float* wk = (const float*)d_in[3];
    const float* bk = (const float*)d_in[4];
    const float* wv = (const float*)d_in[5];
    const float* bv = (const float*)d_in[6];
    const float* wo = (const float*)d_in[7];
    const float* bo = (const float*)d_in[8];

    // Flat workspace, 142.6 MB total (proven OK R4-R12)
    char* base = (char*)d_ws;
    unsigned short* xb     = (unsigned short*)(base + 0);          // 16.8M
    unsigned short* wqkvt  = (unsigned short*)(base + 16777216);   // 50.3M
    unsigned short* wot    = (unsigned short*)(base + 67108864);   // 33.6M
    unsigned short* qbuf   = (unsigned short*)(base + 100663296);  // 16.8M
    unsigned short* kbuf   = (unsigned short*)(base + 117440512);  // 4.2M
    unsigned short* vtbuf  = (unsigned short*)(base + 121634816);  // 4.2M
    unsigned short* merged = (unsigned short*)(base + 125829120);  // 16.8M

    const float QSCALE = 0.08838834764831845f * 1.4426950408889634f;  // 1/sqrt(128) * log2(e)

    // 1) fused pre-pass: weight transposes + x cast (one launch; R12-proven)
    prepass_kernel<<<dim3(192, 64), 256, 0, stream>>>(wq, wk, wv, wo, x, wqkvt, wot, xb);
    // 2) fused Q|K|V projection (BK=64, R11-proven best; grid 48x16=768)
    qkv_gemm_kernel<<<dim3(6144 / 128, SEQ / 128), 256, 0, stream>>>(
        xb, wqkvt, bq, bk, bv, qbuf, kbuf, vtbuf, QSCALE);
    // 3) flash attention into merged (QBLK=256, 512 thr, grid 8x32)
    attn_kernel<<<dim3(SEQ / 256, NHEADS), 512, 0, stream>>>(qbuf, kbuf, vtbuf, merged);
    // 4) output projection -> fp32 d_out (BK=64; grid 32x16=512)
    gemm_bf16_kernel<<<dim3(HIDDEN / 128, SEQ / 128), 256, 0, stream>>>(
        merged, wot, bo, (float*)d_out, SEQ, HIDDEN, HIDDEN, 1.0f);
}